// Round 1
// baseline (100.738 us; speedup 1.0000x reference)
//
#include <hip/hip_runtime.h>
#include <hip/hip_bf16.h>

typedef __attribute__((ext_vector_type(8))) short  short8_t;
typedef __attribute__((ext_vector_type(4))) float  float4_t;
typedef __attribute__((ext_vector_type(4))) int    int4_t;

#define BM 64
#define BN 256
#define BK 64
#define LSTR (BK + 8)   // 72 bf16 = 144 B row stride (breaks pow2 bank conflicts, keeps 16B align)

__device__ __forceinline__ unsigned short f2bf(float f) {
    unsigned int u = __builtin_bit_cast(unsigned int, f);
    u += 0x7FFFu + ((u >> 16) & 1u);          // RNE
    return (unsigned short)(u >> 16);
}
__device__ __forceinline__ unsigned int pack2(float a, float b) {
    return (unsigned int)f2bf(a) | ((unsigned int)f2bf(b) << 16);
}

// ---- pre-pass: W2 f32 -> bf16 into workspace (E*F = 262144 elems) ----
__global__ void cvt_w2_kernel(const float* __restrict__ W2, unsigned short* __restrict__ W2b) {
    const int i = (blockIdx.x * blockDim.x + threadIdx.x) * 4;
    const float4_t v = *reinterpret_cast<const float4_t*>(W2 + i);
    unsigned long long p = (unsigned long long)pack2(v[0], v[1])
                         | ((unsigned long long)pack2(v[2], v[3]) << 32);
    *reinterpret_cast<unsigned long long*>(W2b + i) = p;
}

// ---- fused: q = cos(x[:,:8])*cos(theta); h = relu(q@W1^T) (LDS only); out = h@W2^T via MFMA ----
template <bool WSOK>
__global__ __launch_bounds__(256, 2)
void ffq_kernel(const float* __restrict__ x,
                const float* __restrict__ theta,
                const float* __restrict__ W1,
                const unsigned short* __restrict__ W2b,
                const float* __restrict__ W2f,
                float* __restrict__ out)
{
    __shared__ __align__(16) unsigned short hs[BM][LSTR];   //  9216 B
    __shared__ __align__(16) unsigned short Bs[BN][LSTR];   // 36864 B

    const int tid  = threadIdx.x;
    const int lane = tid & 63;
    const int w    = tid >> 6;      // wave 0..3
    const int wr   = w >> 1;        // wave row-group 0..1 (32 rows each)
    const int wc   = w & 1;         // wave col-group 0..1 (128 cols each)
    const int rowbase = blockIdx.x * BM;

    // ---- per-thread q[8] for row (tid & 63), kept in registers ----
    const int myrow = tid & 63;
    float q[8];
    {
        const float* xp = x + (size_t)(rowbase + myrow) * 256;
        const float4_t x0 = *reinterpret_cast<const float4_t*>(xp);
        const float4_t x1 = *reinterpret_cast<const float4_t*>(xp + 4);
        #pragma unroll
        for (int j = 0; j < 4; ++j) {
            q[j]     = __cosf(x0[j]) * __cosf(theta[j]);
            q[4 + j] = __cosf(x1[j]) * __cosf(theta[4 + j]);
        }
    }
    const int fg = tid >> 6;  // this thread's f-group (0..3) within each K-chunk

    float4_t acc[2][8];
    #pragma unroll
    for (int i = 0; i < 2; ++i)
        #pragma unroll
        for (int j = 0; j < 8; ++j)
            acc[i][j] = (float4_t){0.f, 0.f, 0.f, 0.f};

    const int lr = lane & 15;
    const int lk = (lane >> 4) * 8;

    for (int kc = 0; kc < 1024; kc += BK) {
        __syncthreads();   // previous chunk fully consumed

        // ---- stage W2 chunk -> Bs[e][kk] (coalesced: 8 threads per e-row) ----
        {
            const int j = tid & 7;          // 16B slice within the 128B row-chunk
            const int ebase = tid >> 3;     // 0..31
            #pragma unroll
            for (int it = 0; it < 8; ++it) {
                const int e = ebase + it * 32;
                if constexpr (WSOK) {
                    const int4_t v = *reinterpret_cast<const int4_t*>(
                        W2b + (size_t)e * 1024 + kc + j * 8);
                    *reinterpret_cast<int4_t*>(&Bs[e][j * 8]) = v;
                } else {
                    const float* src = W2f + (size_t)e * 1024 + kc + j * 8;
                    const float4_t v0 = *reinterpret_cast<const float4_t*>(src);
                    const float4_t v1 = *reinterpret_cast<const float4_t*>(src + 4);
                    int4_t p;
                    p[0] = (int)pack2(v0[0], v0[1]);
                    p[1] = (int)pack2(v0[2], v0[3]);
                    p[2] = (int)pack2(v1[0], v1[1]);
                    p[3] = (int)pack2(v1[2], v1[3]);
                    *reinterpret_cast<int4_t*>(&Bs[e][j * 8]) = p;
                }
            }
        }

        // ---- compute h chunk: this thread -> row=myrow, f in [fg*16, fg*16+16) ----
        {
            float s[16];
            #pragma unroll
            for (int i = 0; i < 16; ++i) {
                const int f = kc + fg * 16 + i;
                const float4_t w0 = *reinterpret_cast<const float4_t*>(W1 + (size_t)f * 8);
                const float4_t w1 = *reinterpret_cast<const float4_t*>(W1 + (size_t)f * 8 + 4);
                float v = q[0] * w0[0] + q[1] * w0[1] + q[2] * w0[2] + q[3] * w0[3]
                        + q[4] * w1[0] + q[5] * w1[1] + q[6] * w1[2] + q[7] * w1[3];
                s[i] = fmaxf(v, 0.0f);
            }
            int4_t p0, p1;
            p0[0] = (int)pack2(s[0],  s[1]);  p0[1] = (int)pack2(s[2],  s[3]);
            p0[2] = (int)pack2(s[4],  s[5]);  p0[3] = (int)pack2(s[6],  s[7]);
            p1[0] = (int)pack2(s[8],  s[9]);  p1[1] = (int)pack2(s[10], s[11]);
            p1[2] = (int)pack2(s[12], s[13]); p1[3] = (int)pack2(s[14], s[15]);
            *reinterpret_cast<int4_t*>(&hs[myrow][fg * 16])     = p0;
            *reinterpret_cast<int4_t*>(&hs[myrow][fg * 16 + 8]) = p1;
        }

        __syncthreads();   // hs + Bs ready

        // ---- MFMA: each wave 32 rows x 128 cols ----
        #pragma unroll
        for (int kk = 0; kk < BK; kk += 32) {
            const short8_t a0 = *reinterpret_cast<const short8_t*>(
                &hs[wr * 32 + 0  + lr][kk + lk]);
            const short8_t a1 = *reinterpret_cast<const short8_t*>(
                &hs[wr * 32 + 16 + lr][kk + lk]);
            #pragma unroll
            for (int cf = 0; cf < 8; ++cf) {
                const short8_t b = *reinterpret_cast<const short8_t*>(
                    &Bs[wc * 128 + cf * 16 + lr][kk + lk]);
                acc[0][cf] = __builtin_amdgcn_mfma_f32_16x16x32_bf16(a0, b, acc[0][cf], 0, 0, 0);
                acc[1][cf] = __builtin_amdgcn_mfma_f32_16x16x32_bf16(a1, b, acc[1][cf], 0, 0, 0);
            }
        }
    }

    // ---- epilogue: C/D layout col=lane&15, row=(lane>>4)*4+reg ----
    const int lq = lane >> 4;
    #pragma unroll
    for (int rf = 0; rf < 2; ++rf) {
        #pragma unroll
        for (int cf = 0; cf < 8; ++cf) {
            #pragma unroll
            for (int r = 0; r < 4; ++r) {
                const int gr = rowbase + wr * 32 + rf * 16 + lq * 4 + r;
                const int gc = wc * 128 + cf * 16 + lr;
                out[(size_t)gr * 256 + gc] = acc[rf][cf][r];
            }
        }
    }
}

extern "C" void kernel_launch(void* const* d_in, const int* in_sizes, int n_in,
                              void* d_out, int out_size, void* d_ws, size_t ws_size,
                              hipStream_t stream) {
    const float* x     = (const float*)d_in[0];   // [8,4096,256]
    const float* theta = (const float*)d_in[1];   // [8]
    const float* W1    = (const float*)d_in[2];   // [1024,8]
    const float* W2    = (const float*)d_in[3];   // [256,1024]
    float* out = (float*)d_out;                   // [8,4096,256] f32

    const bool wsok = (ws_size >= (size_t)256 * 1024 * sizeof(unsigned short));
    unsigned short* W2b = (unsigned short*)d_ws;

    if (wsok) {
        // 262144 elems, 4 per thread -> 256 blocks x 256 threads exactly
        cvt_w2_kernel<<<256, 256, 0, stream>>>(W2, W2b);
        ffq_kernel<true><<<512, 256, 0, stream>>>(x, theta, W1, W2b, W2, out);
    } else {
        ffq_kernel<false><<<512, 256, 0, stream>>>(x, theta, W1, nullptr, W2, out);
    }
}

// Round 2
// 41.888 us; speedup vs baseline: 2.4050x; 2.4050x over previous
//
#include <hip/hip_runtime.h>
#include <hip/hip_bf16.h>

typedef __attribute__((ext_vector_type(8))) short  short8_t;
typedef __attribute__((ext_vector_type(4))) float  float4_t;
typedef __attribute__((ext_vector_type(4))) int    int4_t;
typedef __attribute__((ext_vector_type(2))) unsigned int uint2_t;

#define BM 64
#define BN 128
#define BK 64
#define HSTR 72   // hs row stride (144 B) -> 2-way (free) on b128 reads

__device__ __forceinline__ unsigned short f2bf(float f) {
    unsigned int u = __builtin_bit_cast(unsigned int, f);
    u += 0x7FFFu + ((u >> 16) & 1u);          // RNE
    return (unsigned short)(u >> 16);
}
__device__ __forceinline__ unsigned int pack2(float a, float b) {
    return (unsigned int)f2bf(a) | ((unsigned int)f2bf(b) << 16);
}
__device__ __forceinline__ void gload_lds16(const void* g, void* l) {
    __builtin_amdgcn_global_load_lds(
        (const __attribute__((address_space(1))) void*)g,
        (__attribute__((address_space(3))) void*)l, 16, 0, 0);
}

// ---- pre-pass: f32 -> bf16 (4 elems/thread) ----
__global__ void cvt_kernel(const float* __restrict__ src, unsigned short* __restrict__ dst) {
    const int i = (blockIdx.x * blockDim.x + threadIdx.x) * 4;
    const float4_t v = *reinterpret_cast<const float4_t*>(src + i);
    unsigned long long p = (unsigned long long)pack2(v[0], v[1])
                         | ((unsigned long long)pack2(v[2], v[3]) << 32);
    *reinterpret_cast<unsigned long long*>(dst + i) = p;
}

// ---- fused: q=cos(x[:,:8])*cos(theta) -> h=relu(q@W1^T) via MFMA (LDS only) -> out=h@W2^T via MFMA ----
template <bool WSOK>
__global__ __launch_bounds__(256, 4)
void ffq_kernel(const float* __restrict__ x,
                const float* __restrict__ theta,
                const float* __restrict__ W1f,
                const unsigned short* __restrict__ W1b,
                const float* __restrict__ W2f,
                const unsigned short* __restrict__ W2b,
                float* __restrict__ out)
{
    __shared__ __align__(16) unsigned short qs[BM][8];       //  1 KB
    __shared__ __align__(16) unsigned short hs[BM][HSTR];    //  9 KB
    __shared__ __align__(16) unsigned short Bs[BN][BK];      // 16 KB (XOR-swizzled slots)

    const int tid  = threadIdx.x;
    const int lane = tid & 63;
    const int w    = tid >> 6;            // wave 0..3
    const int bid  = blockIdx.x;
    const int rowbase = (bid >> 1) * BM;
    const int colbase = (bid & 1) * BN;

    // ---- q prologue: wave 0 computes q[64][8] -> LDS (bf16) ----
    if (w == 0) {
        const float* xp = x + (size_t)(rowbase + lane) * 256;
        const float4_t x0 = *reinterpret_cast<const float4_t*>(xp);
        const float4_t x1 = *reinterpret_cast<const float4_t*>(xp + 4);
        float qv[8];
        #pragma unroll
        for (int j = 0; j < 4; ++j) {
            qv[j]     = __cosf(x0[j]) * __cosf(theta[j]);
            qv[4 + j] = __cosf(x1[j]) * __cosf(theta[4 + j]);
        }
        int4_t pq;
        pq[0] = (int)pack2(qv[0], qv[1]);
        pq[1] = (int)pack2(qv[2], qv[3]);
        pq[2] = (int)pack2(qv[4], qv[5]);
        pq[3] = (int)pack2(qv[6], qv[7]);
        *reinterpret_cast<int4_t*>(&qs[lane][0]) = pq;
    }
    __syncthreads();

    // ---- hoist q B-frags (one per 16-row m-tile); only k-group 0 lanes hold data, rest zero ----
    short8_t qf[4];
    #pragma unroll
    for (int mt = 0; mt < 4; ++mt) {
        short8_t v = {0, 0, 0, 0, 0, 0, 0, 0};
        if (lane < 16) v = *reinterpret_cast<const short8_t*>(&qs[mt * 16 + lane][0]);
        qf[mt] = v;
    }

    float4_t acc[2][4];
    #pragma unroll
    for (int i = 0; i < 2; ++i)
        #pragma unroll
        for (int j = 0; j < 4; ++j)
            acc[i][j] = (float4_t){0.f, 0.f, 0.f, 0.f};

    const int lr  = lane & 15;
    const int lkg = lane >> 4;            // 0..3
    const int lk  = lkg * 8;
    const int er  = lane >> 3;            // 0..7 (row within an 8-row DMA group)
    const int js  = lane & 7;             // 16B slot within a 128B row

    for (int kc = 0; kc < 1024; kc += BK) {
        __syncthreads();                  // previous chunk fully consumed

        // ---- stage W2 chunk -> Bs (swizzled slots; linear LDS dest) ----
        #pragma unroll
        for (int it = 0; it < 4; ++it) {
            const int e = w * 32 + it * 8 + er;
            const int srccol = ((js ^ (e & 7)) << 3);   // pre-swizzled global source
            if constexpr (WSOK) {
                const unsigned short* src = W2b + (size_t)(colbase + e) * 1024 + kc + srccol;
                gload_lds16(src, &Bs[w * 32 + it * 8][0]);
            } else {
                const float* src = W2f + (size_t)(colbase + e) * 1024 + kc + srccol;
                const float4_t v0 = *reinterpret_cast<const float4_t*>(src);
                const float4_t v1 = *reinterpret_cast<const float4_t*>(src + 4);
                int4_t p;
                p[0] = (int)pack2(v0[0], v0[1]);
                p[1] = (int)pack2(v0[2], v0[3]);
                p[2] = (int)pack2(v1[0], v1[1]);
                p[3] = (int)pack2(v1[2], v1[3]);
                *reinterpret_cast<int4_t*>(&Bs[e][js * 8]) = p;
            }
        }

        // ---- W1 A-frag for this wave's 16 f-rows (K=8 zero-padded to 32) ----
        short8_t af = {0, 0, 0, 0, 0, 0, 0, 0};
        if (lane < 16) {
            if constexpr (WSOK) {
                af = *reinterpret_cast<const short8_t*>(W1b + (size_t)(kc + w * 16 + lane) * 8);
            } else {
                const float* src = W1f + (size_t)(kc + w * 16 + lane) * 8;
                const float4_t v0 = *reinterpret_cast<const float4_t*>(src);
                const float4_t v1 = *reinterpret_cast<const float4_t*>(src + 4);
                int4_t p;
                p[0] = (int)pack2(v0[0], v0[1]);
                p[1] = (int)pack2(v0[2], v0[3]);
                p[2] = (int)pack2(v1[0], v1[1]);
                p[3] = (int)pack2(v1[2], v1[3]);
                af = __builtin_bit_cast(short8_t, p);
            }
        }

        // ---- h-phase: D[f][m] = W1 x q^T; relu; pack 4 consecutive f -> one b64 LDS write ----
        #pragma unroll
        for (int mt = 0; mt < 4; ++mt) {
            float4_t d = __builtin_amdgcn_mfma_f32_16x16x32_bf16(
                af, qf[mt], (float4_t){0.f, 0.f, 0.f, 0.f}, 0, 0, 0);
            uint2_t pk;
            pk[0] = pack2(fmaxf(d[0], 0.f), fmaxf(d[1], 0.f));
            pk[1] = pack2(fmaxf(d[2], 0.f), fmaxf(d[3], 0.f));
            *reinterpret_cast<uint2_t*>(&hs[mt * 16 + lr][w * 16 + lkg * 4]) = pk;
        }

        __syncthreads();                  // hs + Bs ready (barrier drains vmcnt for DMA)

        // ---- main MFMA: each wave 32 rows x 64 cols ----
        const int wr = w >> 1, wc = w & 1;
        #pragma unroll
        for (int kk = 0; kk < BK; kk += 32) {
            const short8_t a0 = *reinterpret_cast<const short8_t*>(
                &hs[wr * 32 + 0  + lr][kk + lk]);
            const short8_t a1 = *reinterpret_cast<const short8_t*>(
                &hs[wr * 32 + 16 + lr][kk + lk]);
            const int s = (kk + lk) >> 3;
            #pragma unroll
            for (int cf = 0; cf < 4; ++cf) {
                const int e = wc * 64 + cf * 16 + lr;
                const short8_t b = *reinterpret_cast<const short8_t*>(
                    &Bs[e][(s ^ (e & 7)) << 3]);
                acc[0][cf] = __builtin_amdgcn_mfma_f32_16x16x32_bf16(a0, b, acc[0][cf], 0, 0, 0);
                acc[1][cf] = __builtin_amdgcn_mfma_f32_16x16x32_bf16(a1, b, acc[1][cf], 0, 0, 0);
            }
        }
    }

    // ---- epilogue: C/D layout col=lane&15, row=(lane>>4)*4+reg ----
    const int wr = w >> 1, wc = w & 1;
    const int lq = lane >> 4;
    #pragma unroll
    for (int rf = 0; rf < 2; ++rf) {
        #pragma unroll
        for (int cf = 0; cf < 4; ++cf) {
            #pragma unroll
            for (int r = 0; r < 4; ++r) {
                const int gr = rowbase + wr * 32 + rf * 16 + lq * 4 + r;
                const int gc = colbase + wc * 64 + cf * 16 + lr;
                out[(size_t)gr * 256 + gc] = acc[rf][cf][r];
            }
        }
    }
}

extern "C" void kernel_launch(void* const* d_in, const int* in_sizes, int n_in,
                              void* d_out, int out_size, void* d_ws, size_t ws_size,
                              hipStream_t stream) {
    const float* x     = (const float*)d_in[0];   // [8,4096,256]
    const float* theta = (const float*)d_in[1];   // [8]
    const float* W1    = (const float*)d_in[2];   // [1024,8]
    const float* W2    = (const float*)d_in[3];   // [256,1024]
    float* out = (float*)d_out;                   // [8,4096,256] f32

    const size_t need = (size_t)(256 * 1024 + 8 * 1024) * sizeof(unsigned short);
    const bool wsok = (ws_size >= need);

    if (wsok) {
        unsigned short* W2b = (unsigned short*)d_ws;          // 256*1024 bf16
        unsigned short* W1b = W2b + 256 * 1024;               // 1024*8 bf16
        cvt_kernel<<<256, 256, 0, stream>>>(W2, W2b);         // 262144/4/256
        cvt_kernel<<<8,   256, 0, stream>>>(W1, W1b);         // 8192/4/256
        ffq_kernel<true><<<1024, 256, 0, stream>>>(x, theta, nullptr, W1b, nullptr, W2b, out);
    } else {
        ffq_kernel<false><<<1024, 256, 0, stream>>>(x, theta, W1, nullptr, W2, nullptr, out);
    }
}